// Round 14
// baseline (438.205 us; speedup 1.0000x reference)
//
#include <hip/hip_runtime.h>

// GSModel pipeline, round 14.
//  - p_b = sum(g1_b) - sum(g2_b) identity (sinkhorn colsum==1) — scores path removed.
//  - bf16 storage; MFMA 16x16x32 bf16; fused gather+GEMM1+GEMM2 k_layer;
//    one-pass slot-CSR; degree-sorted gather balance; W direct-from-global GEMM;
//    8-wide gather edge loop.
//  - REVERTED: nontemporal CSR scatter store (round-13 regression: 2B NT stores
//    became ~94MB of RMW write traffic, k_prep 106->117us). Plain cached store.
//  - NEW: CSR build processes 2 independent edges/thread — two atomic+store
//    latency chains in flight per thread (edge phase is latency-bound, VALU 2%).

constexpr int NNODE = 32768;
constexpr int NEDGE = 524288;

typedef __attribute__((ext_vector_type(8))) short bf16x8;
typedef __attribute__((ext_vector_type(8))) unsigned short ushort8;
typedef __attribute__((ext_vector_type(4))) float f32x4;

__device__ __forceinline__ float bf2f(unsigned short u) {
  return __uint_as_float((unsigned)u << 16);
}
__device__ __forceinline__ unsigned short f2bf(float f) {
  unsigned u = __float_as_uint(f);
  return (unsigned short)((u + 0x7FFFu + ((u >> 16) & 1u)) >> 16);
}
__device__ __forceinline__ unsigned packbf(float a, float b) {
  return (unsigned)f2bf(a) | ((unsigned)f2bf(b) << 16);
}

// ---------------- fused prep: conv (16384) | wprep (96) | CSR build (2048 x 2 edges) ----------------
__global__ __launch_bounds__(256) void k_prep(
    const float* __restrict__ f1, const float* __restrict__ f2,
    unsigned short* __restrict__ hb0,
    const float* __restrict__ gw1, const float* __restrict__ gw2,
    unsigned short* __restrict__ Wt,
    const int* __restrict__ e1, const int* __restrict__ e2,
    int* __restrict__ cnt, unsigned short* __restrict__ srcs64) {
  __shared__ float sh[64][65];
  int b = blockIdx.x, t = threadIdx.x;
  if (b < 16384) {
    // f32 -> bf16 feature convert
    size_t i = (size_t)b * 256 + t;     // 4,194,304 chunks of 4
    const float* src = (i < 2097152) ? (f1 + i * 4) : (f2 + (i - 2097152) * 4);
    float4 v = *(const float4*)src;
    ushort4 o;
    o.x = f2bf(v.x); o.y = f2bf(v.y); o.z = f2bf(v.z); o.w = f2bf(v.w);
    *(ushort4*)(hb0 + i * 4) = o;
  } else if (b < 16480) {
    // weight transpose + convert + k-chunked layout: Wt[mat][k0/32][n][k%32]
    int bb = b - 16384;                 // 96 = 6 mats x 16 tiles of 64x64
    int mat = bb >> 4, tile = bb & 15;
    int tr = (tile >> 2) * 64, tc = (tile & 3) * 64;   // tr = k-range, tc = n-range
    const float* src = (mat < 3) ? (gw1 + (size_t)mat * 65536) : (gw2 + (size_t)(mat - 3) * 65536);
#pragma unroll
    for (int i = 0; i < 4; i++) {
      int c = t + i * 256;              // 1024 float4 chunks
      int row = c >> 4, c4 = (c & 15) * 4;
      float4 v = *(const float4*)(src + (size_t)(tr + row) * 256 + tc + c4);
      sh[row][c4] = v.x; sh[row][c4 + 1] = v.y; sh[row][c4 + 2] = v.z; sh[row][c4 + 3] = v.w;
    }
    __syncthreads();
#pragma unroll
    for (int i = 0; i < 2; i++) {
      int c = t + i * 256;              // 512 chunks of 8 bf16
      int n = c >> 3, kc = (c & 7) * 8; // n local, k local (within 64x64 tile)
      unsigned short e[8];
#pragma unroll
      for (int j = 0; j < 8; j++) e[j] = f2bf(sh[kc + j][n]);
      uint4 o;
      o.x = e[0] | ((unsigned)e[1] << 16);
      o.y = e[2] | ((unsigned)e[3] << 16);
      o.z = e[4] | ((unsigned)e[5] << 16);
      o.w = e[6] | ((unsigned)e[7] << 16);
      int kg = tr + kc;                 // global k, 8-aligned
      size_t idx = (size_t)mat * 65536 + (size_t)(kg >> 5) * 8192 + (size_t)(tc + n) * 32 + (kg & 31);
      *(uint4*)(Wt + idx) = o;
    }
  } else {
    // one-pass CSR build: 2 independent edges per thread (two latency chains in flight)
    int bb = b - 16480;                 // 2048
    int side = bb >> 10;
    int e = (bb & 1023) * 512 + t * 2;
    const int* ei = (side ? e2 : e1);
    int s0 = ei[e], s1 = ei[e + 1];
    int d0 = ei[NEDGE + e], d1 = ei[NEDGE + e + 1];
    int sl0 = atomicAdd(&cnt[side * NNODE + d0], 1);
    int sl1 = atomicAdd(&cnt[side * NNODE + d1], 1);
    if (sl0 < 64) srcs64[(((size_t)side * NNODE + d0) << 6) + sl0] = (unsigned short)s0;
    if (sl1 < 64) srcs64[(((size_t)side * NNODE + d1) << 6) + sl1] = (unsigned short)s1;
  }
}

// ---------------- per-group degree sort: perm[i] = row index of i-th smallest deg ----------------
__global__ __launch_bounds__(128) void k_sortdeg(const int* __restrict__ cnt,
                                                 unsigned char* __restrict__ perm) {
  __shared__ int s[128];
  int g = blockIdx.x;                   // 512 = 2 sides x 256 groups
  int side = g >> 8, grp = g & 255;
  int t = threadIdx.x;
  int deg = cnt[side * NNODE + grp * 128 + t];
  s[t] = (deg << 8) | t;
  __syncthreads();
  for (int k = 2; k <= 128; k <<= 1)
    for (int j = k >> 1; j > 0; j >>= 1) {
      int ixj = t ^ j;
      if (ixj > t) {
        int a = s[t], b2 = s[ixj];
        bool up = ((t & k) == 0);
        if ((a > b2) == up) { s[t] = b2; s[ixj] = a; }
      }
      __syncthreads();
    }
  perm[(size_t)side * NNODE + grp * 128 + t] = (unsigned char)(s[t] & 255);
}

// ---------------- fused layer: gather(+BN) -> GEMM1(relu) -> GEMM2 + stats ----------------
// grid 512 (2 sides x 256 row-blocks of 128), 512 thr = 8 waves (2m x 4n), wave tile 64x64.
// LDS 68KB: sA/sA2 [128][512B] at [0,64K), red 4KB at [64K,68K). 2 blocks/CU.
// W read directly from global (L2-resident, chunked [8][256][32]) — no inner barriers.
template <bool BN>
__global__ __launch_bounds__(512, 4) void k_layer(
    const unsigned short* __restrict__ x,      // [2N][256] prev features
    const int* __restrict__ cnt,               // [2][NNODE] degrees
    const unsigned short* __restrict__ srcs64, // [2][NNODE][64] source ids
    const unsigned char* __restrict__ perm,    // [2][NNODE] degree-sorted row order
    const float* __restrict__ pstats,          // [2][2][256] prev layer (BN only)
    const float* __restrict__ pgamma, const float* __restrict__ pbeta,
    const unsigned short* __restrict__ w1t,    // chunked [8][256][32] bf16
    const unsigned short* __restrict__ w2t,
    const float* __restrict__ b1, const float* __restrict__ b2,
    float* __restrict__ stats,                 // [2][2][256] this layer
    unsigned short* __restrict__ hout) {
  __shared__ __align__(16) char smem[69632];
  char* sA = smem;                 // [128][512B] swizzled bf16
  char* sA2 = smem;                // alias
  float2* red = (float2*)(smem + 65536);   // [256][2]
  int tid = threadIdx.x;
  int lane = tid & 63, wid = tid >> 6;
  int wm = wid & 1, wn = wid >> 1;
  int q = lane >> 4, r = lane & 15;
  const int swA = (r & 7) << 4;
  int b = blockIdx.x;
  int side = b >> 8;
  size_t grow0 = (size_t)side * NNODE + (size_t)(b & 255) * 128;

  // ============ gather phase: aggregate 128 rows into sA (degree-balanced order) ============
  {
    int hw = tid >> 5, sub = tid & 31;   // half-wave owns 8 rows via perm
    float sc[8], shf[8];
    if (BN) {
      int c0 = sub * 8;
      const float* cs = pstats + side * 512;
      const float invn = 1.f / 32768.f;
#pragma unroll
      for (int j = 0; j < 8; j++) {
        float mu = cs[c0 + j] * invn;
        float var = cs[256 + c0 + j] * invn - mu * mu;
        float s = pgamma[c0 + j] * rsqrtf(var + 1e-5f);
        sc[j] = s; shf[j] = pbeta[c0 + j] - mu * s;
      }
    }
    const uint4* X = (const uint4*)x;    // 32 uint4 per row
    size_t rbase = (size_t)side * NNODE;
    const int* degs = cnt + side * NNODE;
    const unsigned short* sr = srcs64 + ((size_t)side * NNODE << 6);
    const unsigned char* pg = perm + (size_t)side * NNODE + (size_t)(b & 255) * 128;
    int nbase = (int)(b & 255) * 128;

#pragma unroll 1
    for (int nn = 0; nn < 8; nn++) {
      int lrow = pg[nn * 16 + hw];       // degree-sorted: all 16 half-waves balanced
      int n = nbase + lrow;
      float a[8];
#pragma unroll
      for (int j = 0; j < 8; j++) a[j] = 0.f;
      auto acc8 = [&](uint4 u, float w) {
        unsigned uu[4] = {u.x, u.y, u.z, u.w};
#pragma unroll
        for (int j = 0; j < 4; j++) {
          float lo = __uint_as_float(uu[j] << 16);
          float hi = __uint_as_float(uu[j] & 0xFFFF0000u);
          if (BN) {
            lo = fmaxf(fmaf(lo, sc[2 * j], shf[2 * j]), 0.f);
            hi = fmaxf(fmaf(hi, sc[2 * j + 1], shf[2 * j + 1]), 0.f);
          }
          a[2 * j] = fmaf(lo, w, a[2 * j]);
          a[2 * j + 1] = fmaf(hi, w, a[2 * j + 1]);
        }
      };
      acc8(X[(rbase + n) * 32 + sub], 2.f);
      int e = n << 6, ee = (n << 6) + degs[n];
      // 8 rows in flight per half-wave; indices via one 16B vector load (e is 8-aligned here)
      for (; e + 7 < ee; e += 8) {
        ushort8 ix = *(const ushort8*)(sr + e);
        uint4 u0 = X[(rbase + ix[0]) * 32 + sub];
        uint4 u1 = X[(rbase + ix[1]) * 32 + sub];
        uint4 u2 = X[(rbase + ix[2]) * 32 + sub];
        uint4 u3 = X[(rbase + ix[3]) * 32 + sub];
        uint4 u4 = X[(rbase + ix[4]) * 32 + sub];
        uint4 u5 = X[(rbase + ix[5]) * 32 + sub];
        uint4 u6 = X[(rbase + ix[6]) * 32 + sub];
        uint4 u7 = X[(rbase + ix[7]) * 32 + sub];
        acc8(u0, 1.f); acc8(u1, 1.f); acc8(u2, 1.f); acc8(u3, 1.f);
        acc8(u4, 1.f); acc8(u5, 1.f); acc8(u6, 1.f); acc8(u7, 1.f);
      }
      if (e + 3 < ee) {
        int i0 = sr[e], i1 = sr[e + 1], i2 = sr[e + 2], i3 = sr[e + 3];
        uint4 u0 = X[(rbase + i0) * 32 + sub];
        uint4 u1 = X[(rbase + i1) * 32 + sub];
        uint4 u2 = X[(rbase + i2) * 32 + sub];
        uint4 u3 = X[(rbase + i3) * 32 + sub];
        acc8(u0, 1.f); acc8(u1, 1.f); acc8(u2, 1.f); acc8(u3, 1.f);
        e += 4;
      }
      for (; e < ee; e++) acc8(X[(rbase + sr[e]) * 32 + sub], 1.f);
      uint4 o;
      o.x = packbf(a[0], a[1]); o.y = packbf(a[2], a[3]);
      o.z = packbf(a[4], a[5]); o.w = packbf(a[6], a[7]);
      *(uint4*)(sA + lrow * 512 + ((sub * 16) ^ ((lrow & 7) << 4))) = o;
    }
  }

  f32x4 acc[4][4];
#pragma unroll
  for (int mi = 0; mi < 4; mi++)
#pragma unroll
    for (int ni = 0; ni < 4; ni++) acc[mi][ni] = (f32x4){0.f, 0.f, 0.f, 0.f};

  __syncthreads();

  // ---- phase 1: C1 = A @ W1 (B direct from global, no barriers) ----
#pragma unroll 2
  for (int k0 = 0; k0 < 256; k0 += 32) {
    bf16x8 af[4], bfr[4];
    int cbA = (k0 * 2 + q * 16) ^ swA;
    const unsigned short* wb = w1t + (size_t)(k0 >> 5) * 8192 + q * 8;
#pragma unroll
    for (int ni = 0; ni < 4; ni++)
      bfr[ni] = *(const bf16x8*)(wb + (size_t)(wn * 64 + ni * 16 + r) * 32);
#pragma unroll
    for (int mi = 0; mi < 4; mi++)
      af[mi] = *(const bf16x8*)(sA + (wm * 64 + mi * 16 + r) * 512 + cbA);
#pragma unroll
    for (int mi = 0; mi < 4; mi++)
#pragma unroll
      for (int ni = 0; ni < 4; ni++)
        acc[mi][ni] = __builtin_amdgcn_mfma_f32_16x16x32_bf16(af[mi], bfr[ni], acc[mi][ni], 0, 0, 0);
  }
  __syncthreads();   // all GEMM1 reads of sA complete

  // epilogue 1: bias + relu -> bf16 into sA2 (alias of sA)
  float b1v[4];
#pragma unroll
  for (int ni = 0; ni < 4; ni++) b1v[ni] = b1[wn * 64 + ni * 16 + r];
#pragma unroll
  for (int mi = 0; mi < 4; mi++)
#pragma unroll
    for (int ni = 0; ni < 4; ni++)
#pragma unroll
      for (int j = 0; j < 4; j++) {
        float o = fmaxf(acc[mi][ni][j] + b1v[ni], 0.f);
        int rowc = wm * 64 + mi * 16 + q * 4 + j;
        int colc = wn * 64 + ni * 16 + r;
        *(unsigned short*)(sA2 + rowc * 512 + ((colc * 2) ^ (((q * 4 + j) & 7) << 4))) = f2bf(o);
      }
#pragma unroll
  for (int mi = 0; mi < 4; mi++)
#pragma unroll
    for (int ni = 0; ni < 4; ni++) acc[mi][ni] = (f32x4){0.f, 0.f, 0.f, 0.f};
  __syncthreads();   // C1 fully written

  // ---- phase 2: C2 = relu(C1) @ W2 (B direct from global, no barriers) ----
#pragma unroll 2
  for (int k0 = 0; k0 < 256; k0 += 32) {
    bf16x8 af[4], bfr[4];
    int cbA = (k0 * 2 + q * 16) ^ swA;
    const unsigned short* wb = w2t + (size_t)(k0 >> 5) * 8192 + q * 8;
#pragma unroll
    for (int ni = 0; ni < 4; ni++)
      bfr[ni] = *(const bf16x8*)(wb + (size_t)(wn * 64 + ni * 16 + r) * 32);
#pragma unroll
    for (int mi = 0; mi < 4; mi++)
      af[mi] = *(const bf16x8*)(sA2 + (wm * 64 + mi * 16 + r) * 512 + cbA);
#pragma unroll
    for (int mi = 0; mi < 4; mi++)
#pragma unroll
      for (int ni = 0; ni < 4; ni++)
        acc[mi][ni] = __builtin_amdgcn_mfma_f32_16x16x32_bf16(af[mi], bfr[ni], acc[mi][ni], 0, 0, 0);
  }
  __syncthreads();   // all GEMM2 reads of sA2 complete

  // epilogue 2: bias, BN stats (shfl + red + atomics), bf16 out via sA2
  float b2v[4];
#pragma unroll
  for (int ni = 0; ni < 4; ni++) b2v[ni] = b2[wn * 64 + ni * 16 + r];
#pragma unroll
  for (int ni = 0; ni < 4; ni++) {
    float ss = 0.f, sq = 0.f;
#pragma unroll
    for (int mi = 0; mi < 4; mi++)
#pragma unroll
      for (int j = 0; j < 4; j++) {
        float o = acc[mi][ni][j] + b2v[ni];
        acc[mi][ni][j] = o;
        ss += o; sq += o * o;
      }
    ss += __shfl_xor(ss, 16, 64); ss += __shfl_xor(ss, 32, 64);
    sq += __shfl_xor(sq, 16, 64); sq += __shfl_xor(sq, 32, 64);
    if (q == 0) {
      float2 w; w.x = ss; w.y = sq;
      red[(wn * 64 + ni * 16 + r) * 2 + wm] = w;
    }
  }
#pragma unroll
  for (int mi = 0; mi < 4; mi++)
#pragma unroll
    for (int ni = 0; ni < 4; ni++)
#pragma unroll
      for (int j = 0; j < 4; j++) {
        int rowc = wm * 64 + mi * 16 + q * 4 + j;
        int colc = wn * 64 + ni * 16 + r;
        *(unsigned short*)(sA2 + rowc * 512 + ((colc * 2) ^ (((q * 4 + j) & 7) << 4))) =
            f2bf(acc[mi][ni][j]);
      }
  __syncthreads();
  float* cs = stats + side * 512;
  if (tid < 256) {
    float2 a = red[tid * 2], c2 = red[tid * 2 + 1];
    atomicAdd(&cs[tid], a.x + c2.x);
    atomicAdd(&cs[256 + tid], a.y + c2.y);
  }
  for (int c = tid; c < 4096; c += 512) {   // 128 rows x 32 chunks of 16B
    int row = c >> 5, cb = (c & 31) * 16;
    float4 v = *(const float4*)(sA2 + row * 512 + (cb ^ ((row & 7) << 4)));
    *(float4*)(hout + (grow0 + row) * 256 + (c & 31) * 8) = v;
  }
}

// ---------------- per-graph sum of relu(bn(h)) ----------------
__global__ __launch_bounds__(256) void k_gsum(
    const unsigned short* __restrict__ h, const float* __restrict__ stats,
    const float* __restrict__ gamma, const float* __restrict__ beta,
    float* __restrict__ sg) {
  int b = blockIdx.x;            // 256 = 2 sides x 128 graphs
  int side = b >> 7, g = b & 127;
  int t = threadIdx.x;
  int c0 = (t & 63) * 4, rg = t >> 6;
  const float* cs = stats + side * 512;
  float sc[4], sh_[4];
#pragma unroll
  for (int j = 0; j < 4; j++) {
    float mu = cs[c0 + j] * (1.f / 32768.f);
    float var = cs[256 + c0 + j] * (1.f / 32768.f) - mu * mu;
    float s = gamma[c0 + j] * rsqrtf(var + 1e-5f);
    sc[j] = s; sh_[j] = beta[c0 + j] - mu * s;
  }
  size_t base = (size_t)side * NNODE + (size_t)g * 256;
  float acc = 0.f;
  for (int k = 0; k < 64; k++) {
    int row = rg + k * 4;
    ushort4 u = *(const ushort4*)(h + (base + row) * 256 + c0);
    acc += fmaxf(fmaf(bf2f(u.x), sc[0], sh_[0]), 0.f);
    acc += fmaxf(fmaf(bf2f(u.y), sc[1], sh_[1]), 0.f);
    acc += fmaxf(fmaf(bf2f(u.z), sc[2], sh_[2]), 0.f);
    acc += fmaxf(fmaf(bf2f(u.w), sc[3], sh_[3]), 0.f);
  }
  __shared__ float red[256];
  red[t] = acc;
  __syncthreads();
  if (t < 64) {
    float s = red[t] + red[t + 64] + red[t + 128] + red[t + 192];
#pragma unroll
    for (int m = 1; m < 64; m <<= 1) s += __shfl_xor(s, m, 64);
    if (t == 0) sg[b] = s;
  }
}

// ---------------- final: p = sg1 - sg2, min-max normalize, exp(-p) ----------------
__global__ void k_final(const float* __restrict__ sg1, const float* __restrict__ sg2,
                        float* __restrict__ out) {
  int t = threadIdx.x;   // 64 threads
  float a = sg1[t] - sg2[t];
  float b = sg1[t + 64] - sg2[t + 64];
  float mn = fminf(a, b), mx = fmaxf(a, b);
#pragma unroll
  for (int msk = 1; msk < 64; msk <<= 1) {
    mn = fminf(mn, __shfl_xor(mn, msk, 64));
    mx = fmaxf(mx, __shfl_xor(mx, msk, 64));
  }
  float inv = 1.0f / (mx - mn);
  out[t] = __expf(-(a - mn) * inv);
  out[t + 64] = __expf(-(b - mn) * inv);
}

// ---------------- host ----------------
extern "C" void kernel_launch(void* const* d_in, const int* in_sizes, int n_in,
                              void* d_out, int out_size, void* d_ws, size_t ws_size,
                              hipStream_t stream) {
  (void)in_sizes; (void)n_in; (void)out_size; (void)ws_size;
  const float* f1 = (const float*)d_in[0];
  const float* f2 = (const float*)d_in[1];
  const int* e1 = (const int*)d_in[2];
  const int* e2 = (const int*)d_in[3];
  const float* gw1 = (const float*)d_in[5];
  const float* gb1 = (const float*)d_in[6];
  const float* gw2 = (const float*)d_in[7];
  const float* gb2 = (const float*)d_in[8];
  const float* gga = (const float*)d_in[9];
  const float* gbe = (const float*)d_in[10];
  float* out = (float*)d_out;

  char* ws = (char*)d_ws;
  size_t o = 0;
  auto alloc = [&](size_t bytes) { void* p = ws + o; o += (bytes + 255) & ~(size_t)255; return p; };
  unsigned short* hb0 = (unsigned short*)alloc(2ull * NNODE * 256 * 2);
  unsigned short* hb1 = (unsigned short*)alloc(2ull * NNODE * 256 * 2);
  unsigned short* Wt = (unsigned short*)alloc(6ull * 65536 * 2);
  // stats (12KB) + cnt (256KB) contiguous -> one memset
  float* stats = (float*)alloc(3 * 1024 * 4);      // [layer][side][{sum,sq}][256]
  int* cnt = (int*)alloc(2 * NNODE * 4);
  float* sg = (float*)alloc(256 * 4);
  unsigned short* srcs64 = (unsigned short*)alloc(2ull * NNODE * 64 * 2);   // 8 MB
  unsigned char* perm = (unsigned char*)alloc(2ull * NNODE);

  (void)hipMemsetAsync(stats, 0, 3 * 1024 * 4 + 2 * NNODE * 4, stream);

  k_prep<<<18528, 256, 0, stream>>>(f1, f2, hb0, gw1, gw2, Wt, e1, e2, cnt, srcs64);
  k_sortdeg<<<512, 128, 0, stream>>>(cnt, perm);

  unsigned short* hb[2] = {hb0, hb1};
  for (int l = 0; l < 3; l++) {
    unsigned short* xin = hb[l & 1];
    unsigned short* hout = hb[1 - (l & 1)];
    if (l == 0)
      k_layer<false><<<512, 512, 0, stream>>>(
          xin, cnt, srcs64, perm, nullptr, nullptr, nullptr,
          Wt + (size_t)l * 65536, Wt + (size_t)(3 + l) * 65536,
          gb1 + l * 256, gb2 + l * 256, stats + l * 1024, hout);
    else
      k_layer<true><<<512, 512, 0, stream>>>(
          xin, cnt, srcs64, perm, stats + (l - 1) * 1024, gga + (l - 1) * 256, gbe + (l - 1) * 256,
          Wt + (size_t)l * 65536, Wt + (size_t)(3 + l) * 65536,
          gb1 + l * 256, gb2 + l * 256, stats + l * 1024, hout);
  }

  k_gsum<<<256, 256, 0, stream>>>(hb1, stats + 2 * 1024, gga + 512, gbe + 512, sg);
  k_final<<<1, 64, 0, stream>>>(sg, sg + 128, out);
}

// Round 15
// 423.283 us; speedup vs baseline: 1.0353x; 1.0353x over previous
//
#include <hip/hip_runtime.h>

// GSModel pipeline, round 15 — best-known composition.
//  - p_b = sum(g1_b) - sum(g2_b) identity (sinkhorn colsum==1) — scores path removed.
//  - bf16 storage; MFMA 16x16x32 bf16; fused gather+GEMM1+GEMM2 k_layer;
//    one-pass slot-CSR; degree-sorted gather balance; W direct-from-global GEMM.
//  - k_prep CSR: round-12 version (1 edge/thread, plain store) — both prep
//    "optimizations" (NT store r13, 2-edge r14) regressed; reverted.
//  - k_layer: keeps r13's 8-wide gather (deeper per-wave MLP, ~-10us/layer).

constexpr int NNODE = 32768;
constexpr int NEDGE = 524288;

typedef __attribute__((ext_vector_type(8))) short bf16x8;
typedef __attribute__((ext_vector_type(8))) unsigned short ushort8;
typedef __attribute__((ext_vector_type(4))) float f32x4;

__device__ __forceinline__ float bf2f(unsigned short u) {
  return __uint_as_float((unsigned)u << 16);
}
__device__ __forceinline__ unsigned short f2bf(float f) {
  unsigned u = __float_as_uint(f);
  return (unsigned short)((u + 0x7FFFu + ((u >> 16) & 1u)) >> 16);
}
__device__ __forceinline__ unsigned packbf(float a, float b) {
  return (unsigned)f2bf(a) | ((unsigned)f2bf(b) << 16);
}

// ---------------- fused prep: conv (16384) | wprep (96) | CSR build (4096) ----------------
__global__ __launch_bounds__(256) void k_prep(
    const float* __restrict__ f1, const float* __restrict__ f2,
    unsigned short* __restrict__ hb0,
    const float* __restrict__ gw1, const float* __restrict__ gw2,
    unsigned short* __restrict__ Wt,
    const int* __restrict__ e1, const int* __restrict__ e2,
    int* __restrict__ cnt, unsigned short* __restrict__ srcs64) {
  __shared__ float sh[64][65];
  int b = blockIdx.x, t = threadIdx.x;
  if (b < 16384) {
    // f32 -> bf16 feature convert
    size_t i = (size_t)b * 256 + t;     // 4,194,304 chunks of 4
    const float* src = (i < 2097152) ? (f1 + i * 4) : (f2 + (i - 2097152) * 4);
    float4 v = *(const float4*)src;
    ushort4 o;
    o.x = f2bf(v.x); o.y = f2bf(v.y); o.z = f2bf(v.z); o.w = f2bf(v.w);
    *(ushort4*)(hb0 + i * 4) = o;
  } else if (b < 16480) {
    // weight transpose + convert + k-chunked layout: Wt[mat][k0/32][n][k%32]
    int bb = b - 16384;                 // 96 = 6 mats x 16 tiles of 64x64
    int mat = bb >> 4, tile = bb & 15;
    int tr = (tile >> 2) * 64, tc = (tile & 3) * 64;   // tr = k-range, tc = n-range
    const float* src = (mat < 3) ? (gw1 + (size_t)mat * 65536) : (gw2 + (size_t)(mat - 3) * 65536);
#pragma unroll
    for (int i = 0; i < 4; i++) {
      int c = t + i * 256;              // 1024 float4 chunks
      int row = c >> 4, c4 = (c & 15) * 4;
      float4 v = *(const float4*)(src + (size_t)(tr + row) * 256 + tc + c4);
      sh[row][c4] = v.x; sh[row][c4 + 1] = v.y; sh[row][c4 + 2] = v.z; sh[row][c4 + 3] = v.w;
    }
    __syncthreads();
#pragma unroll
    for (int i = 0; i < 2; i++) {
      int c = t + i * 256;              // 512 chunks of 8 bf16
      int n = c >> 3, kc = (c & 7) * 8; // n local, k local (within 64x64 tile)
      unsigned short e[8];
#pragma unroll
      for (int j = 0; j < 8; j++) e[j] = f2bf(sh[kc + j][n]);
      uint4 o;
      o.x = e[0] | ((unsigned)e[1] << 16);
      o.y = e[2] | ((unsigned)e[3] << 16);
      o.z = e[4] | ((unsigned)e[5] << 16);
      o.w = e[6] | ((unsigned)e[7] << 16);
      int kg = tr + kc;                 // global k, 8-aligned
      size_t idx = (size_t)mat * 65536 + (size_t)(kg >> 5) * 8192 + (size_t)(tc + n) * 32 + (kg & 31);
      *(uint4*)(Wt + idx) = o;
    }
  } else {
    // one-pass CSR build: slot-append into fixed-capacity [node][64] ushort buckets
    int bb = b - 16480;                 // 4096
    int side = bb >> 11;
    int e = (bb & 2047) * 256 + t;
    const int* ei = (side ? e2 : e1);
    int s = ei[e], d = ei[NEDGE + e];
    int slot = atomicAdd(&cnt[side * NNODE + d], 1);
    if (slot < 64)
      srcs64[(((size_t)side * NNODE + d) << 6) + slot] = (unsigned short)s;
  }
}

// ---------------- per-group degree sort: perm[i] = row index of i-th smallest deg ----------------
__global__ __launch_bounds__(128) void k_sortdeg(const int* __restrict__ cnt,
                                                 unsigned char* __restrict__ perm) {
  __shared__ int s[128];
  int g = blockIdx.x;                   // 512 = 2 sides x 256 groups
  int side = g >> 8, grp = g & 255;
  int t = threadIdx.x;
  int deg = cnt[side * NNODE + grp * 128 + t];
  s[t] = (deg << 8) | t;
  __syncthreads();
  for (int k = 2; k <= 128; k <<= 1)
    for (int j = k >> 1; j > 0; j >>= 1) {
      int ixj = t ^ j;
      if (ixj > t) {
        int a = s[t], b2 = s[ixj];
        bool up = ((t & k) == 0);
        if ((a > b2) == up) { s[t] = b2; s[ixj] = a; }
      }
      __syncthreads();
    }
  perm[(size_t)side * NNODE + grp * 128 + t] = (unsigned char)(s[t] & 255);
}

// ---------------- fused layer: gather(+BN) -> GEMM1(relu) -> GEMM2 + stats ----------------
// grid 512 (2 sides x 256 row-blocks of 128), 512 thr = 8 waves (2m x 4n), wave tile 64x64.
// LDS 68KB: sA/sA2 [128][512B] at [0,64K), red 4KB at [64K,68K). 2 blocks/CU.
// W read directly from global (L2-resident, chunked [8][256][32]) — no inner barriers.
template <bool BN>
__global__ __launch_bounds__(512, 4) void k_layer(
    const unsigned short* __restrict__ x,      // [2N][256] prev features
    const int* __restrict__ cnt,               // [2][NNODE] degrees
    const unsigned short* __restrict__ srcs64, // [2][NNODE][64] source ids
    const unsigned char* __restrict__ perm,    // [2][NNODE] degree-sorted row order
    const float* __restrict__ pstats,          // [2][2][256] prev layer (BN only)
    const float* __restrict__ pgamma, const float* __restrict__ pbeta,
    const unsigned short* __restrict__ w1t,    // chunked [8][256][32] bf16
    const unsigned short* __restrict__ w2t,
    const float* __restrict__ b1, const float* __restrict__ b2,
    float* __restrict__ stats,                 // [2][2][256] this layer
    unsigned short* __restrict__ hout) {
  __shared__ __align__(16) char smem[69632];
  char* sA = smem;                 // [128][512B] swizzled bf16
  char* sA2 = smem;                // alias
  float2* red = (float2*)(smem + 65536);   // [256][2]
  int tid = threadIdx.x;
  int lane = tid & 63, wid = tid >> 6;
  int wm = wid & 1, wn = wid >> 1;
  int q = lane >> 4, r = lane & 15;
  const int swA = (r & 7) << 4;
  int b = blockIdx.x;
  int side = b >> 8;
  size_t grow0 = (size_t)side * NNODE + (size_t)(b & 255) * 128;

  // ============ gather phase: aggregate 128 rows into sA (degree-balanced order) ============
  {
    int hw = tid >> 5, sub = tid & 31;   // half-wave owns 8 rows via perm
    float sc[8], shf[8];
    if (BN) {
      int c0 = sub * 8;
      const float* cs = pstats + side * 512;
      const float invn = 1.f / 32768.f;
#pragma unroll
      for (int j = 0; j < 8; j++) {
        float mu = cs[c0 + j] * invn;
        float var = cs[256 + c0 + j] * invn - mu * mu;
        float s = pgamma[c0 + j] * rsqrtf(var + 1e-5f);
        sc[j] = s; shf[j] = pbeta[c0 + j] - mu * s;
      }
    }
    const uint4* X = (const uint4*)x;    // 32 uint4 per row
    size_t rbase = (size_t)side * NNODE;
    const int* degs = cnt + side * NNODE;
    const unsigned short* sr = srcs64 + ((size_t)side * NNODE << 6);
    const unsigned char* pg = perm + (size_t)side * NNODE + (size_t)(b & 255) * 128;
    int nbase = (int)(b & 255) * 128;

#pragma unroll 1
    for (int nn = 0; nn < 8; nn++) {
      int lrow = pg[nn * 16 + hw];       // degree-sorted: all 16 half-waves balanced
      int n = nbase + lrow;
      float a[8];
#pragma unroll
      for (int j = 0; j < 8; j++) a[j] = 0.f;
      auto acc8 = [&](uint4 u, float w) {
        unsigned uu[4] = {u.x, u.y, u.z, u.w};
#pragma unroll
        for (int j = 0; j < 4; j++) {
          float lo = __uint_as_float(uu[j] << 16);
          float hi = __uint_as_float(uu[j] & 0xFFFF0000u);
          if (BN) {
            lo = fmaxf(fmaf(lo, sc[2 * j], shf[2 * j]), 0.f);
            hi = fmaxf(fmaf(hi, sc[2 * j + 1], shf[2 * j + 1]), 0.f);
          }
          a[2 * j] = fmaf(lo, w, a[2 * j]);
          a[2 * j + 1] = fmaf(hi, w, a[2 * j + 1]);
        }
      };
      acc8(X[(rbase + n) * 32 + sub], 2.f);
      int e = n << 6, ee = (n << 6) + degs[n];
      // 8 rows in flight per half-wave; indices via one 16B vector load (e is 8-aligned here)
      for (; e + 7 < ee; e += 8) {
        ushort8 ix = *(const ushort8*)(sr + e);
        uint4 u0 = X[(rbase + ix[0]) * 32 + sub];
        uint4 u1 = X[(rbase + ix[1]) * 32 + sub];
        uint4 u2 = X[(rbase + ix[2]) * 32 + sub];
        uint4 u3 = X[(rbase + ix[3]) * 32 + sub];
        uint4 u4 = X[(rbase + ix[4]) * 32 + sub];
        uint4 u5 = X[(rbase + ix[5]) * 32 + sub];
        uint4 u6 = X[(rbase + ix[6]) * 32 + sub];
        uint4 u7 = X[(rbase + ix[7]) * 32 + sub];
        acc8(u0, 1.f); acc8(u1, 1.f); acc8(u2, 1.f); acc8(u3, 1.f);
        acc8(u4, 1.f); acc8(u5, 1.f); acc8(u6, 1.f); acc8(u7, 1.f);
      }
      if (e + 3 < ee) {
        int i0 = sr[e], i1 = sr[e + 1], i2 = sr[e + 2], i3 = sr[e + 3];
        uint4 u0 = X[(rbase + i0) * 32 + sub];
        uint4 u1 = X[(rbase + i1) * 32 + sub];
        uint4 u2 = X[(rbase + i2) * 32 + sub];
        uint4 u3 = X[(rbase + i3) * 32 + sub];
        acc8(u0, 1.f); acc8(u1, 1.f); acc8(u2, 1.f); acc8(u3, 1.f);
        e += 4;
      }
      for (; e < ee; e++) acc8(X[(rbase + sr[e]) * 32 + sub], 1.f);
      uint4 o;
      o.x = packbf(a[0], a[1]); o.y = packbf(a[2], a[3]);
      o.z = packbf(a[4], a[5]); o.w = packbf(a[6], a[7]);
      *(uint4*)(sA + lrow * 512 + ((sub * 16) ^ ((lrow & 7) << 4))) = o;
    }
  }

  f32x4 acc[4][4];
#pragma unroll
  for (int mi = 0; mi < 4; mi++)
#pragma unroll
    for (int ni = 0; ni < 4; ni++) acc[mi][ni] = (f32x4){0.f, 0.f, 0.f, 0.f};

  __syncthreads();

  // ---- phase 1: C1 = A @ W1 (B direct from global, no barriers) ----
#pragma unroll 2
  for (int k0 = 0; k0 < 256; k0 += 32) {
    bf16x8 af[4], bfr[4];
    int cbA = (k0 * 2 + q * 16) ^ swA;
    const unsigned short* wb = w1t + (size_t)(k0 >> 5) * 8192 + q * 8;
#pragma unroll
    for (int ni = 0; ni < 4; ni++)
      bfr[ni] = *(const bf16x8*)(wb + (size_t)(wn * 64 + ni * 16 + r) * 32);
#pragma unroll
    for (int mi = 0; mi < 4; mi++)
      af[mi] = *(const bf16x8*)(sA + (wm * 64 + mi * 16 + r) * 512 + cbA);
#pragma unroll
    for (int mi = 0; mi < 4; mi++)
#pragma unroll
      for (int ni = 0; ni < 4; ni++)
        acc[mi][ni] = __builtin_amdgcn_mfma_f32_16x16x32_bf16(af[mi], bfr[ni], acc[mi][ni], 0, 0, 0);
  }
  __syncthreads();   // all GEMM1 reads of sA complete

  // epilogue 1: bias + relu -> bf16 into sA2 (alias of sA)
  float b1v[4];
#pragma unroll
  for (int ni = 0; ni < 4; ni++) b1v[ni] = b1[wn * 64 + ni * 16 + r];
#pragma unroll
  for (int mi = 0; mi < 4; mi++)
#pragma unroll
    for (int ni = 0; ni < 4; ni++)
#pragma unroll
      for (int j = 0; j < 4; j++) {
        float o = fmaxf(acc[mi][ni][j] + b1v[ni], 0.f);
        int rowc = wm * 64 + mi * 16 + q * 4 + j;
        int colc = wn * 64 + ni * 16 + r;
        *(unsigned short*)(sA2 + rowc * 512 + ((colc * 2) ^ (((q * 4 + j) & 7) << 4))) = f2bf(o);
      }
#pragma unroll
  for (int mi = 0; mi < 4; mi++)
#pragma unroll
    for (int ni = 0; ni < 4; ni++) acc[mi][ni] = (f32x4){0.f, 0.f, 0.f, 0.f};
  __syncthreads();   // C1 fully written

  // ---- phase 2: C2 = relu(C1) @ W2 (B direct from global, no barriers) ----
#pragma unroll 2
  for (int k0 = 0; k0 < 256; k0 += 32) {
    bf16x8 af[4], bfr[4];
    int cbA = (k0 * 2 + q * 16) ^ swA;
    const unsigned short* wb = w2t + (size_t)(k0 >> 5) * 8192 + q * 8;
#pragma unroll
    for (int ni = 0; ni < 4; ni++)
      bfr[ni] = *(const bf16x8*)(wb + (size_t)(wn * 64 + ni * 16 + r) * 32);
#pragma unroll
    for (int mi = 0; mi < 4; mi++)
      af[mi] = *(const bf16x8*)(sA2 + (wm * 64 + mi * 16 + r) * 512 + cbA);
#pragma unroll
    for (int mi = 0; mi < 4; mi++)
#pragma unroll
      for (int ni = 0; ni < 4; ni++)
        acc[mi][ni] = __builtin_amdgcn_mfma_f32_16x16x32_bf16(af[mi], bfr[ni], acc[mi][ni], 0, 0, 0);
  }
  __syncthreads();   // all GEMM2 reads of sA2 complete

  // epilogue 2: bias, BN stats (shfl + red + atomics), bf16 out via sA2
  float b2v[4];
#pragma unroll
  for (int ni = 0; ni < 4; ni++) b2v[ni] = b2[wn * 64 + ni * 16 + r];
#pragma unroll
  for (int ni = 0; ni < 4; ni++) {
    float ss = 0.f, sq = 0.f;
#pragma unroll
    for (int mi = 0; mi < 4; mi++)
#pragma unroll
      for (int j = 0; j < 4; j++) {
        float o = acc[mi][ni][j] + b2v[ni];
        acc[mi][ni][j] = o;
        ss += o; sq += o * o;
      }
    ss += __shfl_xor(ss, 16, 64); ss += __shfl_xor(ss, 32, 64);
    sq += __shfl_xor(sq, 16, 64); sq += __shfl_xor(sq, 32, 64);
    if (q == 0) {
      float2 w; w.x = ss; w.y = sq;
      red[(wn * 64 + ni * 16 + r) * 2 + wm] = w;
    }
  }
#pragma unroll
  for (int mi = 0; mi < 4; mi++)
#pragma unroll
    for (int ni = 0; ni < 4; ni++)
#pragma unroll
      for (int j = 0; j < 4; j++) {
        int rowc = wm * 64 + mi * 16 + q * 4 + j;
        int colc = wn * 64 + ni * 16 + r;
        *(unsigned short*)(sA2 + rowc * 512 + ((colc * 2) ^ (((q * 4 + j) & 7) << 4))) =
            f2bf(acc[mi][ni][j]);
      }
  __syncthreads();
  float* cs = stats + side * 512;
  if (tid < 256) {
    float2 a = red[tid * 2], c2 = red[tid * 2 + 1];
    atomicAdd(&cs[tid], a.x + c2.x);
    atomicAdd(&cs[256 + tid], a.y + c2.y);
  }
  for (int c = tid; c < 4096; c += 512) {   // 128 rows x 32 chunks of 16B
    int row = c >> 5, cb = (c & 31) * 16;
    float4 v = *(const float4*)(sA2 + row * 512 + (cb ^ ((row & 7) << 4)));
    *(float4*)(hout + (grow0 + row) * 256 + (c & 31) * 8) = v;
  }
}

// ---------------- per-graph sum of relu(bn(h)) ----------------
__global__ __launch_bounds__(256) void k_gsum(
    const unsigned short* __restrict__ h, const float* __restrict__ stats,
    const float* __restrict__ gamma, const float* __restrict__ beta,
    float* __restrict__ sg) {
  int b = blockIdx.x;            // 256 = 2 sides x 128 graphs
  int side = b >> 7, g = b & 127;
  int t = threadIdx.x;
  int c0 = (t & 63) * 4, rg = t >> 6;
  const float* cs = stats + side * 512;
  float sc[4], sh_[4];
#pragma unroll
  for (int j = 0; j < 4; j++) {
    float mu = cs[c0 + j] * (1.f / 32768.f);
    float var = cs[256 + c0 + j] * (1.f / 32768.f) - mu * mu;
    float s = gamma[c0 + j] * rsqrtf(var + 1e-5f);
    sc[j] = s; sh_[j] = beta[c0 + j] - mu * s;
  }
  size_t base = (size_t)side * NNODE + (size_t)g * 256;
  float acc = 0.f;
  for (int k = 0; k < 64; k++) {
    int row = rg + k * 4;
    ushort4 u = *(const ushort4*)(h + (base + row) * 256 + c0);
    acc += fmaxf(fmaf(bf2f(u.x), sc[0], sh_[0]), 0.f);
    acc += fmaxf(fmaf(bf2f(u.y), sc[1], sh_[1]), 0.f);
    acc += fmaxf(fmaf(bf2f(u.z), sc[2], sh_[2]), 0.f);
    acc += fmaxf(fmaf(bf2f(u.w), sc[3], sh_[3]), 0.f);
  }
  __shared__ float red[256];
  red[t] = acc;
  __syncthreads();
  if (t < 64) {
    float s = red[t] + red[t + 64] + red[t + 128] + red[t + 192];
#pragma unroll
    for (int m = 1; m < 64; m <<= 1) s += __shfl_xor(s, m, 64);
    if (t == 0) sg[b] = s;
  }
}

// ---------------- final: p = sg1 - sg2, min-max normalize, exp(-p) ----------------
__global__ void k_final(const float* __restrict__ sg1, const float* __restrict__ sg2,
                        float* __restrict__ out) {
  int t = threadIdx.x;   // 64 threads
  float a = sg1[t] - sg2[t];
  float b = sg1[t + 64] - sg2[t + 64];
  float mn = fminf(a, b), mx = fmaxf(a, b);
#pragma unroll
  for (int msk = 1; msk < 64; msk <<= 1) {
    mn = fminf(mn, __shfl_xor(mn, msk, 64));
    mx = fmaxf(mx, __shfl_xor(mx, msk, 64));
  }
  float inv = 1.0f / (mx - mn);
  out[t] = __expf(-(a - mn) * inv);
  out[t + 64] = __expf(-(b - mn) * inv);
}

// ---------------- host ----------------
extern "C" void kernel_launch(void* const* d_in, const int* in_sizes, int n_in,
                              void* d_out, int out_size, void* d_ws, size_t ws_size,
                              hipStream_t stream) {
  (void)in_sizes; (void)n_in; (void)out_size; (void)ws_size;
  const float* f1 = (const float*)d_in[0];
  const float* f2 = (const float*)d_in[1];
  const int* e1 = (const int*)d_in[2];
  const int* e2 = (const int*)d_in[3];
  const float* gw1 = (const float*)d_in[5];
  const float* gb1 = (const float*)d_in[6];
  const float* gw2 = (const float*)d_in[7];
  const float* gb2 = (const float*)d_in[8];
  const float* gga = (const float*)d_in[9];
  const float* gbe = (const float*)d_in[10];
  float* out = (float*)d_out;

  char* ws = (char*)d_ws;
  size_t o = 0;
  auto alloc = [&](size_t bytes) { void* p = ws + o; o += (bytes + 255) & ~(size_t)255; return p; };
  unsigned short* hb0 = (unsigned short*)alloc(2ull * NNODE * 256 * 2);
  unsigned short* hb1 = (unsigned short*)alloc(2ull * NNODE * 256 * 2);
  unsigned short* Wt = (unsigned short*)alloc(6ull * 65536 * 2);
  // stats (12KB) + cnt (256KB) contiguous -> one memset
  float* stats = (float*)alloc(3 * 1024 * 4);      // [layer][side][{sum,sq}][256]
  int* cnt = (int*)alloc(2 * NNODE * 4);
  float* sg = (float*)alloc(256 * 4);
  unsigned short* srcs64 = (unsigned short*)alloc(2ull * NNODE * 64 * 2);   // 8 MB
  unsigned char* perm = (unsigned char*)alloc(2ull * NNODE);

  (void)hipMemsetAsync(stats, 0, 3 * 1024 * 4 + 2 * NNODE * 4, stream);

  k_prep<<<20576, 256, 0, stream>>>(f1, f2, hb0, gw1, gw2, Wt, e1, e2, cnt, srcs64);
  k_sortdeg<<<512, 128, 0, stream>>>(cnt, perm);

  unsigned short* hb[2] = {hb0, hb1};
  for (int l = 0; l < 3; l++) {
    unsigned short* xin = hb[l & 1];
    unsigned short* hout = hb[1 - (l & 1)];
    if (l == 0)
      k_layer<false><<<512, 512, 0, stream>>>(
          xin, cnt, srcs64, perm, nullptr, nullptr, nullptr,
          Wt + (size_t)l * 65536, Wt + (size_t)(3 + l) * 65536,
          gb1 + l * 256, gb2 + l * 256, stats + l * 1024, hout);
    else
      k_layer<true><<<512, 512, 0, stream>>>(
          xin, cnt, srcs64, perm, stats + (l - 1) * 1024, gga + (l - 1) * 256, gbe + (l - 1) * 256,
          Wt + (size_t)l * 65536, Wt + (size_t)(3 + l) * 65536,
          gb1 + l * 256, gb2 + l * 256, stats + l * 1024, hout);
  }

  k_gsum<<<256, 256, 0, stream>>>(hb1, stats + 2 * 1024, gga + 512, gbe + 512, sg);
  k_final<<<1, 64, 0, stream>>>(sg, sg + 128, out);
}